// Round 1
// baseline (75.845 us; speedup 1.0000x reference)
//
#include <hip/hip_runtime.h>
#include <math.h>

// Problem constants
// IN_C=3, DIM=256, OUT_C=256, N_PIECES=20, BATCH=16, SET_N=128

// ---------------------------------------------------------------------------
// K1: H1[k][b*128+n] = relu(sum_c w1[k,c]*x[b,c,n] + b1[k])   (256 x 2048)
// ---------------------------------------------------------------------------
__global__ __launch_bounds__(256) void conv1_kernel(
    const float* __restrict__ x, const float* __restrict__ w1,
    const float* __restrict__ b1, float* __restrict__ H1)
{
    int gid = blockIdx.x * 256 + threadIdx.x;   // 0 .. 524287
    int k  = gid >> 11;          // /2048
    int bn = gid & 2047;
    int b  = bn >> 7, n = bn & 127;
    const float* xb = x + b * 384 + n;          // x[b][c][n], c stride 128
    float acc = fmaf(w1[k*3+0], xb[0],
                fmaf(w1[k*3+1], xb[128],
                fmaf(w1[k*3+2], xb[256], b1[k])));
    H1[gid] = fmaxf(acc, 0.0f);
}

// ---------------------------------------------------------------------------
// K2: H2[b][d][n] = sum_k W2[d,k] * H1[k][b*128+n] + b2[d]
// GEMM 256(d) x 2048(bn) x 256(k), 64x64 tiles, 256 thr, 4x4 micro-tile
// ---------------------------------------------------------------------------
__global__ __launch_bounds__(256) void conv2_gemm_kernel(
    const float* __restrict__ W2, const float* __restrict__ H1,
    const float* __restrict__ b2, float* __restrict__ H2)
{
    __shared__ float As[16][64];   // As[k][d]
    __shared__ float Bs[16][64];   // Bs[k][bn]
    int tid = threadIdx.x;
    int tx = tid & 15, ty = tid >> 4;
    int bn0 = blockIdx.x * 64;     // 32 tiles
    int d0  = blockIdx.y * 64;     // 4 tiles
    float acc[4][4] = {};
    for (int k0 = 0; k0 < 256; k0 += 16) {
        int e = tid * 4;
        int d_off = e >> 4, k_off = e & 15;     // k_off in {0,4,8,12}
        float4 av = *(const float4*)(W2 + (d0 + d_off) * 256 + k0 + k_off);
        As[k_off+0][d_off] = av.x; As[k_off+1][d_off] = av.y;
        As[k_off+2][d_off] = av.z; As[k_off+3][d_off] = av.w;
        int r = e >> 6, c = e & 63;
        *(float4*)(&Bs[r][c]) = *(const float4*)(H1 + (k0 + r) * 2048 + bn0 + c);
        __syncthreads();
        #pragma unroll
        for (int kk = 0; kk < 16; kk++) {
            float4 a  = *(const float4*)(&As[kk][ty*4]);
            float4 bv = *(const float4*)(&Bs[kk][tx*4]);
            float aa[4] = {a.x, a.y, a.z, a.w};
            float bb[4] = {bv.x, bv.y, bv.z, bv.w};
            #pragma unroll
            for (int i = 0; i < 4; i++)
                #pragma unroll
                for (int j = 0; j < 4; j++)
                    acc[i][j] = fmaf(aa[i], bb[j], acc[i][j]);
        }
        __syncthreads();
    }
    int bn_base = bn0 + tx * 4;
    int b = bn_base >> 7, n = bn_base & 127;   // 64-tile lies inside one b
    #pragma unroll
    for (int i = 0; i < 4; i++) {
        int d = d0 + ty * 4 + i;
        float bias = b2[d];
        float4 o = make_float4(acc[i][0]+bias, acc[i][1]+bias,
                               acc[i][2]+bias, acc[i][3]+bias);
        *(float4*)(H2 + b * 32768 + d * 128 + n) = o;
    }
}

// ---------------------------------------------------------------------------
// K3: FSPool. One wave per row r = b*256+c (4096 rows). 4 waves/block.
// s[r][n] = H2 flat. Computes pooled[r] = sum_j softmax_i(s_i*scal_j - B_i)
//           . s  *  w[c,j]
// ---------------------------------------------------------------------------
__device__ __forceinline__ float pool_weight(const float* __restrict__ pw, int j)
{
    // replicate: ratio=j/127; idx_f=20*ratio; idx=floor; frac=idx_f-idx
    float ratio = (float)j / 127.0f;
    float idx_f = 20.0f * ratio;
    int idx = (int)idx_f;                 // j>=0 -> floor
    float frac = idx_f - (float)idx;
    int idx2 = idx + 1 > 20 ? 20 : idx + 1;
    float left = pw[idx], right = pw[idx2];
    return (1.0f - frac) * left + frac * right;
}

__global__ __launch_bounds__(256) void fspool_kernel(
    const float* __restrict__ s_glob,    // [4096][128]
    const float* __restrict__ pool_w,    // [256][21]
    float* __restrict__ pooled)          // [4096]  (= [b][c])
{
    const float LOG2E = 1.4426950408889634f;
    int wave = threadIdx.x >> 6;
    int lane = threadIdx.x & 63;
    int row  = blockIdx.x * 4 + wave;

    __shared__ float2 sb[4][128];        // (s_i, Bsum_i * log2e)

    const float* srow = s_glob + row * 128;
    float2 sv = *(const float2*)(srow + lane * 2);
    sb[wave][lane*2]   = make_float2(sv.x, 0.0f);
    sb[wave][lane*2+1] = make_float2(sv.y, 0.0f);
    __syncthreads();

    // Bsum for i = lane, lane+64
    float si0 = sb[wave][lane].x;
    float si1 = sb[wave][lane + 64].x;
    float B0 = 0.0f, B1 = 0.0f;
    #pragma unroll 8
    for (int j = 0; j < 128; j++) {
        float sj = sb[wave][j].x;
        B0 += fabsf(si0 - sj);
        B1 += fabsf(si1 - sj);
    }
    sb[wave][lane].y      = B0 * LOG2E;
    sb[wave][lane + 64].y = B1 * LOG2E;
    __syncthreads();

    // softmax positions j = lane, lane+64 (scaling[j] = 127 - 2j), log2 domain
    float scal0 = (float)(127 - 2 * lane) * LOG2E;
    float scal1 = (float)(127 - 2 * (lane + 64)) * LOG2E;
    float m0 = -1e30f, m1 = -1e30f;
    #pragma unroll 8
    for (int i = 0; i < 128; i++) {
        float2 v = sb[wave][i];
        m0 = fmaxf(m0, fmaf(v.x, scal0, -v.y));
        m1 = fmaxf(m1, fmaf(v.x, scal1, -v.y));
    }
    float se0 = 0.0f, sd0 = 0.0f, se1 = 0.0f, sd1 = 0.0f;
    #pragma unroll 4
    for (int i = 0; i < 128; i++) {
        float2 v = sb[wave][i];
        float e0 = exp2f(fmaf(v.x, scal0, -v.y) - m0);
        float e1 = exp2f(fmaf(v.x, scal1, -v.y) - m1);
        se0 += e0; sd0 = fmaf(e0, v.x, sd0);
        se1 += e1; sd1 = fmaf(e1, v.x, sd1);
    }
    float xs0 = sd0 / se0;
    float xs1 = sd1 / se1;

    int c = row & 255;
    const float* pw = pool_w + c * 21;
    float part = xs0 * pool_weight(pw, lane) + xs1 * pool_weight(pw, lane + 64);

    #pragma unroll
    for (int off = 32; off > 0; off >>= 1)
        part += __shfl_xor(part, off);
    if (lane == 0) pooled[row] = part;
}

// ---------------------------------------------------------------------------
// K4: fused MLP tail. One block per batch row.
// z1 = relu(pooled@lin1_w.T+b); z2 = z1@lin2_w.T+b; z3 = relu(z2@cls1_w.T+b);
// out = z3@cls2_w.T+b   (16 x 10)
// ---------------------------------------------------------------------------
__device__ __forceinline__ void dense256(
    const float* __restrict__ W, const float* __restrict__ Bv,
    const float* in_lds, float* out_lds, int tid, bool do_relu)
{
    float acc = Bv[tid];
    const float* wrow = W + tid * 256;
    #pragma unroll 8
    for (int k = 0; k < 256; k += 4) {
        float4 wv = *(const float4*)(wrow + k);
        float4 iv = *(const float4*)(in_lds + k);
        acc = fmaf(wv.x, iv.x, acc);
        acc = fmaf(wv.y, iv.y, acc);
        acc = fmaf(wv.z, iv.z, acc);
        acc = fmaf(wv.w, iv.w, acc);
    }
    out_lds[tid] = do_relu ? fmaxf(acc, 0.0f) : acc;
}

__global__ __launch_bounds__(256) void tail_kernel(
    const float* __restrict__ pooled,
    const float* __restrict__ W1, const float* __restrict__ B1,
    const float* __restrict__ W2, const float* __restrict__ B2,
    const float* __restrict__ W3, const float* __restrict__ B3,
    const float* __restrict__ W4, const float* __restrict__ B4,
    float* __restrict__ out)
{
    __shared__ float za[256], zb[256];
    int b = blockIdx.x, tid = threadIdx.x;
    za[tid] = pooled[b * 256 + tid];
    __syncthreads();
    dense256(W1, B1, za, zb, tid, true);    // lin1 + relu
    __syncthreads();
    dense256(W2, B2, zb, za, tid, false);   // lin2
    __syncthreads();
    dense256(W3, B3, za, zb, tid, true);    // cls1 + relu
    __syncthreads();
    // cls2: 10 outputs, 16 lanes each
    if (tid < 160) {
        int o = tid >> 4, kk = tid & 15;
        float p = 0.0f;
        const float* wrow = W4 + o * 256;
        #pragma unroll
        for (int k = kk * 16; k < kk * 16 + 16; k++)
            p = fmaf(zb[k], wrow[k], p);
        p += __shfl_down(p, 8, 16);
        p += __shfl_down(p, 4, 16);
        p += __shfl_down(p, 2, 16);
        p += __shfl_down(p, 1, 16);
        if (kk == 0) out[b * 10 + o] = p + B4[o];
    }
}

// ---------------------------------------------------------------------------
extern "C" void kernel_launch(void* const* d_in, const int* in_sizes, int n_in,
                              void* d_out, int out_size, void* d_ws, size_t ws_size,
                              hipStream_t stream)
{
    (void)in_sizes; (void)n_in; (void)out_size; (void)ws_size;
    const float* x       = (const float*)d_in[0];   // (16,3,128)
    const float* conv1_w = (const float*)d_in[1];   // (256,3)
    const float* conv1_b = (const float*)d_in[2];
    const float* conv2_w = (const float*)d_in[3];   // (256,256)
    const float* conv2_b = (const float*)d_in[4];
    const float* pool_w  = (const float*)d_in[5];   // (256,21)
    const float* lin1_w  = (const float*)d_in[6];
    const float* lin1_b  = (const float*)d_in[7];
    const float* lin2_w  = (const float*)d_in[8];
    const float* lin2_b  = (const float*)d_in[9];
    const float* cls1_w  = (const float*)d_in[10];
    const float* cls1_b  = (const float*)d_in[11];
    const float* cls2_w  = (const float*)d_in[12];  // (10,256)
    const float* cls2_b  = (const float*)d_in[13];
    float* out = (float*)d_out;

    float* ws     = (float*)d_ws;
    float* H1     = ws;                 // 256*2048 = 524288 floats
    float* H2     = ws + 524288;        // 16*256*128 = 524288 floats
    float* pooled = ws + 1048576;       // 4096 floats

    conv1_kernel<<<2048, 256, 0, stream>>>(x, conv1_w, conv1_b, H1);
    conv2_gemm_kernel<<<dim3(32, 4), 256, 0, stream>>>(conv2_w, H1, conv2_b, H2);
    fspool_kernel<<<1024, 256, 0, stream>>>(H2, pool_w, pooled);
    tail_kernel<<<16, 256, 0, stream>>>(pooled,
        lin1_w, lin1_b, lin2_w, lin2_b, cls1_w, cls1_b, cls2_w, cls2_b, out);
}

// Round 2
// 62.219 us; speedup vs baseline: 1.2190x; 1.2190x over previous
//
#include <hip/hip_runtime.h>
#include <math.h>

// IN_C=3, DIM=256, OUT_C=256, N_PIECES=20, BATCH=16, SET_N=128

#if __has_builtin(__builtin_amdgcn_exp2f)
#define EXP2F(x) __builtin_amdgcn_exp2f(x)
#else
#define EXP2F(x) exp2f(x)
#endif

// ---------------------------------------------------------------------------
// K1: fused conv1+conv2.
// H2[b][d][n] = b2[d] + sum_k W2[d,k] * relu(b1[k] + sum_c w1[k,c]*x[b,c,n])
// Tile: 32 d x 64 bn, grid (32 bn-tiles, 8 d-tiles) = 256 blocks, 256 thr.
// ---------------------------------------------------------------------------
__global__ __launch_bounds__(256) void conv12_kernel(
    const float* __restrict__ x, const float* __restrict__ w1,
    const float* __restrict__ b1, const float* __restrict__ W2,
    const float* __restrict__ b2, float* __restrict__ H2)
{
    __shared__ float xs[3][64];
    __shared__ float As[16][32];   // As[kk][dl] = W2[d0+dl][k0+kk]
    __shared__ float Bs[16][64];   // Bs[kk][nl] = relu(conv1)

    int tid = threadIdx.x;
    int bx  = blockIdx.x;          // bn0 = bx*64
    int d0  = blockIdx.y * 32;
    int b   = bx >> 1;
    int n0  = (bx & 1) * 64;

    if (tid < 192) {
        int c = tid >> 6, n = tid & 63;
        xs[c][n] = x[b * 384 + c * 128 + n0 + n];
    }
    __syncthreads();

    int tx = tid & 15, ty = tid >> 4;           // tx: n/4, ty: d/2
    int dl = tid & 31, kk2 = tid >> 5;          // As staging map
    float acc[2][4] = {};

    for (int k0 = 0; k0 < 256; k0 += 16) {
        // stage As (W2 sub-tile, transposed to [k][d])
        float2 wv = *(const float2*)(W2 + (d0 + dl) * 256 + k0 + kk2 * 2);
        As[kk2 * 2 + 0][dl] = wv.x;
        As[kk2 * 2 + 1][dl] = wv.y;
        // stage Bs: conv1 on the fly (k uniform per wave per q)
        #pragma unroll
        for (int q = 0; q < 4; q++) {
            int idx = tid + 256 * q;
            int krel = idx >> 6, nl = idx & 63;
            int k = k0 + krel;
            float h = fmaf(w1[k * 3 + 0], xs[0][nl],
                      fmaf(w1[k * 3 + 1], xs[1][nl],
                      fmaf(w1[k * 3 + 2], xs[2][nl], b1[k])));
            Bs[krel][nl] = fmaxf(h, 0.0f);
        }
        __syncthreads();
        #pragma unroll
        for (int kk = 0; kk < 16; kk++) {
            float2 a  = *(const float2*)(&As[kk][ty * 2]);
            float4 bv = *(const float4*)(&Bs[kk][tx * 4]);
            acc[0][0] = fmaf(a.x, bv.x, acc[0][0]);
            acc[0][1] = fmaf(a.x, bv.y, acc[0][1]);
            acc[0][2] = fmaf(a.x, bv.z, acc[0][2]);
            acc[0][3] = fmaf(a.x, bv.w, acc[0][3]);
            acc[1][0] = fmaf(a.y, bv.x, acc[1][0]);
            acc[1][1] = fmaf(a.y, bv.y, acc[1][1]);
            acc[1][2] = fmaf(a.y, bv.z, acc[1][2]);
            acc[1][3] = fmaf(a.y, bv.w, acc[1][3]);
        }
        __syncthreads();
    }

    #pragma unroll
    for (int i = 0; i < 2; i++) {
        int d = d0 + ty * 2 + i;
        float bias = b2[d];
        float4 o = make_float4(acc[i][0] + bias, acc[i][1] + bias,
                               acc[i][2] + bias, acc[i][3] + bias);
        *(float4*)(H2 + b * 32768 + d * 128 + n0 + tx * 4) = o;
    }
}

// ---------------------------------------------------------------------------
// K2: FSPool. One wave per row r = b*256+c (4096 rows), 4 waves/block.
// pooled[r] = sum_j [softmax_i(s_i*scal_j - B_i) . s] * w[c,j]
// ---------------------------------------------------------------------------
__device__ __forceinline__ float pool_weight(const float* __restrict__ pw, int j)
{
    float ratio = (float)j / 127.0f;
    float idx_f = 20.0f * ratio;
    int idx = (int)idx_f;
    float frac = idx_f - (float)idx;
    int idx2 = idx + 1 > 20 ? 20 : idx + 1;
    return (1.0f - frac) * pw[idx] + frac * pw[idx2];
}

__global__ __launch_bounds__(256) void fspool_kernel(
    const float* __restrict__ s_glob,    // [4096][128]
    const float* __restrict__ pool_w,    // [256][21]
    float* __restrict__ pooled)          // [4096]
{
    const float LOG2E = 1.4426950408889634f;
    int wave = threadIdx.x >> 6;
    int lane = threadIdx.x & 63;
    int row  = blockIdx.x * 4 + wave;

    __shared__ float2 sb[4][128];        // (s_i, Bsum_i * log2e)

    const float* srow = s_glob + row * 128;
    float2 sv = *(const float2*)(srow + lane * 2);
    sb[wave][lane * 2]     = make_float2(sv.x, 0.0f);
    sb[wave][lane * 2 + 1] = make_float2(sv.y, 0.0f);
    __syncthreads();

    float si0 = sb[wave][lane].x;
    float si1 = sb[wave][lane + 64].x;
    float B0 = 0.0f, B1 = 0.0f;
    #pragma unroll 8
    for (int j = 0; j < 128; j++) {
        float sj = sb[wave][j].x;
        B0 += fabsf(si0 - sj);
        B1 += fabsf(si1 - sj);
    }
    sb[wave][lane].y      = B0 * LOG2E;
    sb[wave][lane + 64].y = B1 * LOG2E;
    __syncthreads();

    float scal0 = (float)(127 - 2 * lane) * LOG2E;
    float scal1 = (float)(127 - 2 * (lane + 64)) * LOG2E;
    float m0 = -1e30f, m1 = -1e30f;
    #pragma unroll 8
    for (int i = 0; i < 128; i++) {
        float2 v = sb[wave][i];
        m0 = fmaxf(m0, fmaf(v.x, scal0, -v.y));
        m1 = fmaxf(m1, fmaf(v.x, scal1, -v.y));
    }
    float se0 = 0.0f, sd0 = 0.0f, se1 = 0.0f, sd1 = 0.0f;
    #pragma unroll 4
    for (int i = 0; i < 128; i++) {
        float2 v = sb[wave][i];
        float e0 = EXP2F(fmaf(v.x, scal0, -v.y) - m0);
        float e1 = EXP2F(fmaf(v.x, scal1, -v.y) - m1);
        se0 += e0; sd0 = fmaf(e0, v.x, sd0);
        se1 += e1; sd1 = fmaf(e1, v.x, sd1);
    }
    float xs0 = sd0 / se0;
    float xs1 = sd1 / se1;

    int c = row & 255;
    const float* pw = pool_w + c * 21;
    float part = xs0 * pool_weight(pw, lane) + xs1 * pool_weight(pw, lane + 64);

    #pragma unroll
    for (int off = 32; off > 0; off >>= 1)
        part += __shfl_xor(part, off);
    if (lane == 0) pooled[row] = part;
}

// ---------------------------------------------------------------------------
// K3: fused MLP tail, 1024 threads/block, one block per batch row.
// Each 256-output dense layer: 4 threads per output (split-K 64 each),
// shfl-reduce partials.
// ---------------------------------------------------------------------------
__device__ __forceinline__ void dense1024(
    const float* __restrict__ W, const float* __restrict__ Bv,
    const float* in_lds, float* out_lds, int tid, bool do_relu)
{
    int o = tid >> 2, p = tid & 3;
    const float* wr = W + o * 256 + p * 64;
    const float* ir = in_lds + p * 64;
    float acc = 0.0f;
    #pragma unroll
    for (int k = 0; k < 64; k += 4) {
        float4 wv = *(const float4*)(wr + k);
        float4 iv = *(const float4*)(ir + k);
        acc = fmaf(wv.x, iv.x, acc);
        acc = fmaf(wv.y, iv.y, acc);
        acc = fmaf(wv.z, iv.z, acc);
        acc = fmaf(wv.w, iv.w, acc);
    }
    acc += __shfl_xor(acc, 1);
    acc += __shfl_xor(acc, 2);
    if (p == 0) {
        acc += Bv[o];
        out_lds[o] = do_relu ? fmaxf(acc, 0.0f) : acc;
    }
}

__global__ __launch_bounds__(1024) void tail_kernel(
    const float* __restrict__ pooled,
    const float* __restrict__ W1, const float* __restrict__ B1,
    const float* __restrict__ W2, const float* __restrict__ B2,
    const float* __restrict__ W3, const float* __restrict__ B3,
    const float* __restrict__ W4, const float* __restrict__ B4,
    float* __restrict__ out)
{
    __shared__ float za[256], zb[256];
    int b = blockIdx.x, tid = threadIdx.x;
    if (tid < 256) za[tid] = pooled[b * 256 + tid];
    __syncthreads();
    dense1024(W1, B1, za, zb, tid, true);    // lin1 + relu
    __syncthreads();
    dense1024(W2, B2, zb, za, tid, false);   // lin2
    __syncthreads();
    dense1024(W3, B3, za, zb, tid, true);    // cls1 + relu
    __syncthreads();
    // cls2: 10 outputs, one wave per output
    if (tid < 640) {
        int o = tid >> 6, kb = tid & 63;
        float4 wv = *(const float4*)(W4 + o * 256 + kb * 4);
        float4 zv = *(const float4*)(zb + kb * 4);
        float p = fmaf(wv.x, zv.x, fmaf(wv.y, zv.y,
                  fmaf(wv.z, zv.z, wv.w * zv.w)));
        #pragma unroll
        for (int off = 32; off > 0; off >>= 1)
            p += __shfl_xor(p, off);
        if (kb == 0) out[b * 10 + o] = p + B4[o];
    }
}

// ---------------------------------------------------------------------------
extern "C" void kernel_launch(void* const* d_in, const int* in_sizes, int n_in,
                              void* d_out, int out_size, void* d_ws, size_t ws_size,
                              hipStream_t stream)
{
    (void)in_sizes; (void)n_in; (void)out_size; (void)ws_size;
    const float* x       = (const float*)d_in[0];   // (16,3,128)
    const float* conv1_w = (const float*)d_in[1];   // (256,3)
    const float* conv1_b = (const float*)d_in[2];
    const float* conv2_w = (const float*)d_in[3];   // (256,256)
    const float* conv2_b = (const float*)d_in[4];
    const float* pool_w  = (const float*)d_in[5];   // (256,21)
    const float* lin1_w  = (const float*)d_in[6];
    const float* lin1_b  = (const float*)d_in[7];
    const float* lin2_w  = (const float*)d_in[8];
    const float* lin2_b  = (const float*)d_in[9];
    const float* cls1_w  = (const float*)d_in[10];
    const float* cls1_b  = (const float*)d_in[11];
    const float* cls2_w  = (const float*)d_in[12];  // (10,256)
    const float* cls2_b  = (const float*)d_in[13];
    float* out = (float*)d_out;

    float* ws     = (float*)d_ws;
    float* H2     = ws;                 // 16*256*128 = 524288 floats
    float* pooled = ws + 524288;        // 4096 floats

    conv12_kernel<<<dim3(32, 8), 256, 0, stream>>>(x, conv1_w, conv1_b,
                                                   conv2_w, conv2_b, H2);
    fspool_kernel<<<1024, 256, 0, stream>>>(H2, pool_w, pooled);
    tail_kernel<<<16, 1024, 0, stream>>>(pooled,
        lin1_w, lin1_b, lin2_w, lin2_b, cls1_w, cls1_b, cls2_w, cls2_b, out);
}